// Round 8
// baseline (24.061 us; speedup 1.0000x reference)
//
#include <hip/hip_runtime.h>

// SVR inference: out[i] = sum_j exp(-|f_i-f_j|^2/50) * alpha[j] + bias
// N=4096, D=64.  Round 8: SINGLE fused dispatch (R5/R7 were wall-flat at
// 19.8us across structural changes -> suspect launch/prep/latency overhead,
// not loop throughput). Per block: convert its 128-row j-chunk fp32->bf16
// into LDS in FRAGMENT order + j-norms/alpha in LDS; B-frags (16 i-rows)
// converted in-register; same 8-tile MFMA+exp2 loop, A-frags via
// ds_read_b128 (2-way bank alias = free). out zeroed by captured
// hipMemsetAsync; bias added by the blockIdx.y==0 blocks.
//
// Frag map (16x16x32 bf16): lane l of tile t, half h holds
//   row = 16*t + (l&15), k = 32*h + (l>>4)*8 .. +7  -> chunk (t*2+h)*64+l.
// A/B frags share the lane->k map => k-permutation cancels in A.B.
// C/D: col=lane&15 (i), row=(lane>>4)*4+reg (j)  [verified m89; R4-R7 passed]
// exp2 domain: exp(-(si+sj-2dot)/50) = exp2(dot*K1 - si2 - sj2),
//   si2 = |f_i|^2*log2(e)/50,  K1 = 2*log2(e)/50.

#define NN 4096
#define DD 64
#define JC 32                   // j-chunks (grid.y); 128 j-rows each
#define JROWS 128
#define NTL 8                   // j-tiles per block

typedef __attribute__((ext_vector_type(8))) short bf16x8;
typedef __attribute__((ext_vector_type(4))) float f32x4;

#define K1 0.057707802f         // 2*log2(e)/50
#define C2 0.028853901f         // log2(e)/50

static __device__ __forceinline__ short f2bf(float f) {
    unsigned int x = __float_as_uint(f);
    x += 0x7fffu + ((x >> 16) & 1u);          // RNE
    return (short)(x >> 16);
}

__global__ __launch_bounds__(256) void svr_fused(const float* __restrict__ F,
                                                 const float* __restrict__ alpha,
                                                 const float* __restrict__ bias,
                                                 float* __restrict__ out) {
    __shared__ bf16x8 jf[NTL * 2 * 64];                 // 16 KB frag-order j-tiles
    __shared__ __align__(16) float sjl[JROWS];          // C2*|f_j|^2
    __shared__ __align__(16) float ajl[JROWS];          // alpha_j

    const int tid  = threadIdx.x;
    const int lane = tid & 63;
    const int wave = tid >> 6;
    const int jBase = blockIdx.y * JROWS;

    // ---- Phase A: j-chunk -> LDS (frag order) + norms + alpha ----
    {
        const int r = tid >> 1;                         // local j-row 0..127
        const int h = tid & 1;                          // k-half
        const float4* src = reinterpret_cast<const float4*>(
            F + (size_t)(jBase + r) * DD + h * 32);
        float4 v[8];
#pragma unroll
        for (int q = 0; q < 8; ++q) v[q] = src[q];      // 128B/thread, coalesced

        float p = 0.f;
#pragma unroll
        for (int q = 0; q < 8; ++q) {
            p = fmaf(v[q].x, v[q].x, p); p = fmaf(v[q].y, v[q].y, p);
            p = fmaf(v[q].z, v[q].z, p); p = fmaf(v[q].w, v[q].w, p);
        }
        p += __shfl_xor(p, 1);                          // join the two halves
        if (h == 0) sjl[r] = p * C2;
        else        ajl[r] = alpha[jBase + r];

        const int tl = r >> 4, rr = r & 15;
#pragma unroll
        for (int kg = 0; kg < 4; ++kg) {
            const float4 a = v[kg * 2], b = v[kg * 2 + 1];
            bf16x8 u;
            u[0] = f2bf(a.x); u[1] = f2bf(a.y); u[2] = f2bf(a.z); u[3] = f2bf(a.w);
            u[4] = f2bf(b.x); u[5] = f2bf(b.y); u[6] = f2bf(b.z); u[7] = f2bf(b.w);
            jf[(tl * 2 + h) * 64 + kg * 16 + rr] = u;
        }
    }

    // ---- B-fragments (this wave's 16 i-rows) in-register + si2 ----
    const int it    = blockIdx.x * 4 + wave;            // i-tile 0..255
    const int iBase = it * 16;
    const int c     = lane & 15;
    const int kg    = lane >> 4;
    const float* fi = F + (size_t)(iBase + c) * DD + kg * 8;
    const float4 w0 = reinterpret_cast<const float4*>(fi)[0];
    const float4 w1 = reinterpret_cast<const float4*>(fi)[1];
    const float4 w2 = reinterpret_cast<const float4*>(fi + 32)[0];
    const float4 w3 = reinterpret_cast<const float4*>(fi + 32)[1];
    bf16x8 b0, b1;
    b0[0] = f2bf(w0.x); b0[1] = f2bf(w0.y); b0[2] = f2bf(w0.z); b0[3] = f2bf(w0.w);
    b0[4] = f2bf(w1.x); b0[5] = f2bf(w1.y); b0[6] = f2bf(w1.z); b0[7] = f2bf(w1.w);
    b1[0] = f2bf(w2.x); b1[1] = f2bf(w2.y); b1[2] = f2bf(w2.z); b1[3] = f2bf(w2.w);
    b1[4] = f2bf(w3.x); b1[5] = f2bf(w3.y); b1[6] = f2bf(w3.z); b1[7] = f2bf(w3.w);

    float q = 0.f;
    q = fmaf(w0.x, w0.x, q); q = fmaf(w0.y, w0.y, q);
    q = fmaf(w0.z, w0.z, q); q = fmaf(w0.w, w0.w, q);
    q = fmaf(w1.x, w1.x, q); q = fmaf(w1.y, w1.y, q);
    q = fmaf(w1.z, w1.z, q); q = fmaf(w1.w, w1.w, q);
    q = fmaf(w2.x, w2.x, q); q = fmaf(w2.y, w2.y, q);
    q = fmaf(w2.z, w2.z, q); q = fmaf(w2.w, w2.w, q);
    q = fmaf(w3.x, w3.x, q); q = fmaf(w3.y, w3.y, q);
    q = fmaf(w3.z, w3.z, q); q = fmaf(w3.w, w3.w, q);
    q += __shfl_xor(q, 16);
    q += __shfl_xor(q, 32);                             // sum over the 4 kg groups
    const float si2 = q * C2;
    const float bv = bias[0];

    __syncthreads();

    // ---- Main: 8 j-tiles of MFMA + exp2 + alpha ----
    f32x4 acc = {0.f, 0.f, 0.f, 0.f};
#pragma unroll
    for (int tl = 0; tl < NTL; ++tl) {
        const bf16x8 a0 = jf[(tl * 2 + 0) * 64 + lane];   // ds_read_b128
        const bf16x8 a1 = jf[(tl * 2 + 1) * 64 + lane];
        f32x4 d0 = {0.f, 0.f, 0.f, 0.f};
        f32x4 d1 = {0.f, 0.f, 0.f, 0.f};
        d0 = __builtin_amdgcn_mfma_f32_16x16x32_bf16(a0, b0, d0, 0, 0, 0);  // k 0..31
        d1 = __builtin_amdgcn_mfma_f32_16x16x32_bf16(a1, b1, d1, 0, 0, 0);  // k 32..63
        // d0[r]+d1[r] = dot(f_j, f_i), j = jBase+16*tl+kg*4+r, i = iBase+c

        const float4 sj = *reinterpret_cast<const float4*>(&sjl[tl * 16 + kg * 4]);
        const float4 aj = *reinterpret_cast<const float4*>(&ajl[tl * 16 + kg * 4]);

        acc.x = fmaf(exp2f(fmaf(d0[0] + d1[0], K1, -(si2 + sj.x))), aj.x, acc.x);
        acc.y = fmaf(exp2f(fmaf(d0[1] + d1[1], K1, -(si2 + sj.y))), aj.y, acc.y);
        acc.z = fmaf(exp2f(fmaf(d0[2] + d1[2], K1, -(si2 + sj.z))), aj.z, acc.z);
        acc.w = fmaf(exp2f(fmaf(d0[3] + d1[3], K1, -(si2 + sj.w))), aj.w, acc.w);
    }

    float s = (acc.x + acc.y) + (acc.z + acc.w);
    s += __shfl_xor(s, 16);
    s += __shfl_xor(s, 32);
    if (lane < 16) {
        if (blockIdx.y == 0) s += bv;                   // bias exactly once per i
        atomicAdd(&out[iBase + lane], s);
    }
}

extern "C" void kernel_launch(void* const* d_in, const int* in_sizes, int n_in,
                              void* d_out, int out_size, void* d_ws, size_t ws_size,
                              hipStream_t stream) {
    const float* F     = (const float*)d_in[0];
    const float* alpha = (const float*)d_in[1];
    const float* bias  = (const float*)d_in[2];
    float* out = (float*)d_out;

    hipMemsetAsync(out, 0, (size_t)out_size * sizeof(float), stream);  // capture-safe
    svr_fused<<<dim3(NN / 64, JC), dim3(256), 0, stream>>>(F, alpha, bias, out);
}

// Round 9
// 21.356 us; speedup vs baseline: 1.1267x; 1.1267x over previous
//
#include <hip/hip_runtime.h>

// SVR inference: out[i] = sum_j exp(-|f_i-f_j|^2/50) * alpha[j] + bias
// N=4096, D=64.  Round 9: atomic-free partials + reduce (decisive overhead
// experiment). R5/R7 flat at 19.8us across loop changes; R8 fusion regressed
// (redundant conversion). Structure: prep (retile fp32->bf16 frag-order Ft,
// norms) -> main grid (64,16): wave computes 16 i-rows x 256 j, writes
// ws[p*4096+i] ONCE (no atomics, no memset) -> reduce: out[i]=bias+sum_p.
//
// Frag map (16x16x32 bf16): lane l of tile t, half h holds
//   row=16*t+(l&15), k=32*h+(l>>4)*8..+7  -> chunk (t*2+h)*64+l.
// A/B frags share lane->k map => k-permutation cancels in A.B.
// C/D: col=lane&15 (i), row=(lane>>4)*4+reg (j)  [verified m89; R4-R8 passed]
// exp2 domain: exp(-(si+sj-2dot)/50) = exp2(dot*K1 - si2 - sj2),
//   sq2[i]=|f_i|^2*log2(e)/50,  K1=2*log2(e)/50.

#define NN 4096
#define DD 64
#define NP 16                  // partials; main block covers 256 j = 16 tiles
#define NT (NN / 16)           // 256 row-tiles

typedef __attribute__((ext_vector_type(8))) short bf16x8;
typedef __attribute__((ext_vector_type(8))) unsigned short u16x8;
typedef __attribute__((ext_vector_type(4))) float f32x4;

#define K1 0.057707802f        // 2*log2(e)/50
#define C2 0.028853901f        // log2(e)/50

static __device__ __forceinline__ unsigned short f2bf(float f) {
    unsigned int x = __float_as_uint(f);
    x += 0x7fffu + ((x >> 16) & 1u);          // RNE
    return (unsigned short)(x >> 16);
}

// ---------- prep: retile+convert; row norms via LDS reduce ----------
__global__ __launch_bounds__(256) void svr_prep(const float* __restrict__ F,
                                                u16x8* __restrict__ Ft,
                                                float* __restrict__ sq2) {
    __shared__ float part[256];
    const int tid = threadIdx.x;
    const int g = blockIdx.x * 256 + tid;           // 0..32767
    const int l = g & 63;
    const int h = (g >> 6) & 1;
    const int t = g >> 7;
    const int row = t * 16 + (l & 15);
    const int k0  = h * 32 + (l >> 4) * 8;

    const float4* src = reinterpret_cast<const float4*>(F + (size_t)row * DD + k0);
    const float4 v0 = src[0];
    const float4 v1 = src[1];
    u16x8 u;
    u[0] = f2bf(v0.x); u[1] = f2bf(v0.y); u[2] = f2bf(v0.z); u[3] = f2bf(v0.w);
    u[4] = f2bf(v1.x); u[5] = f2bf(v1.y); u[6] = f2bf(v1.z); u[7] = f2bf(v1.w);
    Ft[g] = u;

    float p = v0.x * v0.x;
    p = fmaf(v0.y, v0.y, p); p = fmaf(v0.z, v0.z, p); p = fmaf(v0.w, v0.w, p);
    p = fmaf(v1.x, v1.x, p); p = fmaf(v1.y, v1.y, p); p = fmaf(v1.z, v1.z, p);
    p = fmaf(v1.w, v1.w, p);
    part[tid] = p;
    __syncthreads();
    if ((tid & 112) == 0) {    // one thread per row: tid in {0..15, 128..143}
        float s = part[tid]      + part[tid + 16] + part[tid + 32] + part[tid + 48]
                + part[tid + 64] + part[tid + 80] + part[tid + 96] + part[tid + 112];
        sq2[row] = s * C2;
    }
}

// ---------- main: 16-tile MFMA+exp2 run, one partial store ----------
__global__ __launch_bounds__(256) void svr_mfma(const bf16x8* __restrict__ Ft,
                                                const float* __restrict__ alpha,
                                                const float* __restrict__ sq2,
                                                float* __restrict__ ws) {
    const int lane = threadIdx.x & 63;
    const int wave = threadIdx.x >> 6;
    const int it   = blockIdx.x * 4 + wave;          // i-tile 0..255
    const int iBase = it * 16;
    const int p    = blockIdx.y;                     // partial 0..15
    const int jt0  = p * (NT / NP);                  // 16 j-tiles
    const int kg   = lane >> 4;
    const int c    = lane & 15;

    const bf16x8 b0 = Ft[it * 128 + lane];           // B-frags: 1KB coalesced
    const bf16x8 b1 = Ft[it * 128 + 64 + lane];
    const float si2 = sq2[iBase + c];

    const float4* sqv = reinterpret_cast<const float4*>(sq2);
    const float4* alv = reinterpret_cast<const float4*>(alpha);

    f32x4 acc = {0.f, 0.f, 0.f, 0.f};

    bf16x8 a0 = Ft[jt0 * 128 + lane];
    bf16x8 a1 = Ft[jt0 * 128 + 64 + lane];
    float4 sj = sqv[jt0 * 4 + kg];
    float4 aj = alv[jt0 * 4 + kg];

#pragma unroll
    for (int k = 0; k < NT / NP; ++k) {
        bf16x8 n0, n1;
        float4 nsj, naj;
        if (k + 1 < NT / NP) {                       // prefetch next tile
            const int jn = jt0 + k + 1;
            n0 = Ft[jn * 128 + lane];
            n1 = Ft[jn * 128 + 64 + lane];
            nsj = sqv[jn * 4 + kg];
            naj = alv[jn * 4 + kg];
        }
        f32x4 d0 = {0.f, 0.f, 0.f, 0.f};
        f32x4 d1 = {0.f, 0.f, 0.f, 0.f};
        d0 = __builtin_amdgcn_mfma_f32_16x16x32_bf16(a0, b0, d0, 0, 0, 0);  // k 0..31
        d1 = __builtin_amdgcn_mfma_f32_16x16x32_bf16(a1, b1, d1, 0, 0, 0);  // k 32..63
        // d0[r]+d1[r] = dot(f_j, f_i), j = 16*(jt0+k)+kg*4+r, i = iBase+c

        acc.x = fmaf(exp2f(fmaf(d0[0] + d1[0], K1, -(si2 + sj.x))), aj.x, acc.x);
        acc.y = fmaf(exp2f(fmaf(d0[1] + d1[1], K1, -(si2 + sj.y))), aj.y, acc.y);
        acc.z = fmaf(exp2f(fmaf(d0[2] + d1[2], K1, -(si2 + sj.z))), aj.z, acc.z);
        acc.w = fmaf(exp2f(fmaf(d0[3] + d1[3], K1, -(si2 + sj.w))), aj.w, acc.w);

        a0 = n0; a1 = n1; sj = nsj; aj = naj;
    }

    float s = (acc.x + acc.y) + (acc.z + acc.w);
    s += __shfl_xor(s, 16);
    s += __shfl_xor(s, 32);
    if (lane < 16) ws[p * NN + iBase + lane] = s;    // plain store, exactly once
}

// ---------- reduce: out[i] = bias + sum_p ws[p][i] ----------
__global__ __launch_bounds__(256) void svr_reduce(const float* __restrict__ ws,
                                                  const float* __restrict__ bias,
                                                  float* __restrict__ out) {
    const int i = blockIdx.x * 256 + threadIdx.x;
    float s = bias[0];
#pragma unroll
    for (int p = 0; p < NP; ++p) s += ws[p * NN + i];
    out[i] = s;
}

// ---------------- launch ----------------
extern "C" void kernel_launch(void* const* d_in, const int* in_sizes, int n_in,
                              void* d_out, int out_size, void* d_ws, size_t ws_size,
                              hipStream_t stream) {
    const float* F     = (const float*)d_in[0];
    const float* alpha = (const float*)d_in[1];
    const float* bias  = (const float*)d_in[2];
    float* out = (float*)d_out;

    u16x8* Ft   = (u16x8*)d_ws;                                   // 512 KB tiled bf16
    float* sq2  = (float*)((char*)d_ws + (size_t)NN * DD * 2);    // 16 KB norms
    float* part = sq2 + NN;                                       // 256 KB partials

    svr_prep<<<dim3(NN * DD / 8 / 256), dim3(256), 0, stream>>>(F, Ft, sq2);
    svr_mfma<<<dim3(NT / 4, NP), dim3(256), 0, stream>>>((const bf16x8*)Ft, alpha, sq2, part);
    svr_reduce<<<dim3(NN / 256), dim3(256), 0, stream>>>(part, bias, out);
}